// Round 12
// baseline (185.390 us; speedup 1.0000x reference)
//
#include <hip/hip_runtime.h>
#include <hip/hip_bf16.h>

typedef __bf16 bf16;
typedef bf16 bf16x8 __attribute__((ext_vector_type(8)));
typedef bf16 bf16x4 __attribute__((ext_vector_type(4)));
typedef float f32x4 __attribute__((ext_vector_type(4)));

#define DHEAD 128
#define SCL2 0.1275500811965365f   // (1/sqrt(128)) * log2(e)
#define NINF (-__builtin_inff())

__device__ __forceinline__ unsigned pk2(float a, float b) {
  bf16 x = (bf16)a, y = (bf16)b;
  unsigned short ux = __builtin_bit_cast(unsigned short, x);
  unsigned short uy = __builtin_bit_cast(unsigned short, y);
  return ((unsigned)uy << 16) | (unsigned)ux;
}

// ws layouts
#define ACC_FLOATS (1024 * 64 * 128)
#define ML_OFF ACC_FLOATS
#define WS_NEED ((size_t)(ACC_FLOATS + 1024 * 64 * 2) * 4)

#define ACC4_FLOATS (2048 * 64 * 128)
#define ML4_OFF ACC4_FLOATS
#define WS_NEED4 ((size_t)(ACC4_FLOATS + 2048 * 64 * 2) * 4)

// ===================== 4-way split kernel (primary path) =====================
// bid: half = bid>>9; w = bid&511; qt = 31-(w>>4); b = w&15.
// Tile range: NT=2(qt+1); t0=half*NT/4, t1=(half+1)*NT/4 (chains <= 16 tiles).
// Single-buffered LDS (24 KB) + two barriers/tile; loads issued between them.
// Q pre-scaled by SCL2 at load (softmax mul folded out).
__global__ __launch_bounds__(256) void fa_split4(
    const float* __restrict__ Q, const float* __restrict__ K,
    const float* __restrict__ V, float* __restrict__ ws, int S)
{
  const int bid  = blockIdx.x;
  const int half = bid >> 9;
  const int w    = bid & 511;
  const int qt   = 31 - (w >> 4);      // long chains dispatch first
  const int b    = w & 15;
  const int blk  = bid;

  const int NT = 2 * (qt + 1);
  const int t0 = (half * NT) >> 2;
  const int t1 = ((half + 1) * NT) >> 2;

  const int tid  = threadIdx.x;
  const int wave = tid >> 6;
  const int lane = tid & 63;
  const int lr   = lane & 15;
  const int lg   = lane >> 4;

  __shared__ bf16 Ks[32][136];
  __shared__ bf16 Vt[DHEAD][40];
  __shared__ bf16 Ps[4][16][40];

  const size_t bo = (size_t)b * S * DHEAD;
  const float* Qb = Q + bo + (size_t)qt * 64 * DHEAD;
  const float* Kb = K + bo;
  const float* Vb = V + bo;
  const int wrow0 = qt * 64 + wave * 16;

  const int j   = tid & 31;
  const int prw = tid >> 5;
  const int d4  = j << 2;
  const int Gw  = (j >> 1) & 3;

  // Q fragments pre-scaled by SCL2 (fp32 mul before bf16 cvt)
  bf16x8 qf[4];
  {
    const float* qr = Qb + (size_t)(wave * 16 + lr) * DHEAD;
    #pragma unroll
    for (int c = 0; c < 4; ++c) {
      const float4 u0 = *reinterpret_cast<const float4*>(qr + c * 32 + lg * 8);
      const float4 u1 = *reinterpret_cast<const float4*>(qr + c * 32 + lg * 8 + 4);
      bf16x8 f;
      f[0] = (bf16)(u0.x * SCL2); f[1] = (bf16)(u0.y * SCL2);
      f[2] = (bf16)(u0.z * SCL2); f[3] = (bf16)(u0.w * SCL2);
      f[4] = (bf16)(u1.x * SCL2); f[5] = (bf16)(u1.y * SCL2);
      f[6] = (bf16)(u1.z * SCL2); f[7] = (bf16)(u1.w * SCL2);
      qf[c] = f;
    }
  }

  f32x4 oacc[8];
  #pragma unroll
  for (int ii = 0; ii < 8; ++ii) oacc[ii] = (f32x4){0.f, 0.f, 0.f, 0.f};
  float m = NINF, l = 0.f;

  float4 kA[2], kB[2], vA[2], vB[2];
  auto load_tile = [&](int kc) {
    #pragma unroll
    for (int ps = 0; ps < 2; ++ps) {
      const int kv = kc + 2 * (prw + 8 * ps);
      const float* kp = Kb + (size_t)kv * DHEAD + d4;
      const float* vp = Vb + (size_t)kv * DHEAD + d4;
      kA[ps] = *reinterpret_cast<const float4*>(kp);
      kB[ps] = *reinterpret_cast<const float4*>(kp + DHEAD);
      vA[ps] = *reinterpret_cast<const float4*>(vp);
      vB[ps] = *reinterpret_cast<const float4*>(vp + DHEAD);
    }
  };
  auto write_tile = [&]() {
    #pragma unroll
    for (int ps = 0; ps < 2; ++ps) {
      const int kvp = prw + 8 * ps;
      bf16x4 ka, kb;
      ka[0] = (bf16)kA[ps].x; ka[1] = (bf16)kA[ps].y;
      ka[2] = (bf16)kA[ps].z; ka[3] = (bf16)kA[ps].w;
      kb[0] = (bf16)kB[ps].x; kb[1] = (bf16)kB[ps].y;
      kb[2] = (bf16)kB[ps].z; kb[3] = (bf16)kB[ps].w;
      *reinterpret_cast<bf16x4*>(&Ks[2 * kvp][d4])     = ka;
      *reinterpret_cast<bf16x4*>(&Ks[2 * kvp + 1][d4]) = kb;
      const int pS = kvp ^ (Gw << 2);
      const float* fa = &vA[ps].x;
      const float* fb = &vB[ps].x;
      #pragma unroll
      for (int c = 0; c < 4; ++c) {
        *reinterpret_cast<unsigned*>(&Vt[d4 + c][2 * pS]) = pk2(fa[c], fb[c]);
      }
    }
  };

  if (t0 < t1) load_tile(t0 * 32);

  for (int t = t0; t < t1; ++t) {
    __syncthreads();                  // previous tile's reads complete
    write_tile();                     // regs hold tile t
    if (t + 1 < t1) load_tile((t + 1) * 32);
    __syncthreads();                  // LDS tile t ready

    const int kc = t * 32;
    if (kc <= wrow0 + 15) {
      f32x4 s0 = {0.f, 0.f, 0.f, 0.f}, s1 = {0.f, 0.f, 0.f, 0.f};
      __builtin_amdgcn_s_setprio(1);
      #pragma unroll
      for (int c = 0; c < 4; ++c) {
        const bf16x8 kf0 = *reinterpret_cast<const bf16x8*>(&Ks[lr][c * 32 + lg * 8]);
        const bf16x8 kf1 = *reinterpret_cast<const bf16x8*>(&Ks[16 + lr][c * 32 + lg * 8]);
        s0 = __builtin_amdgcn_mfma_f32_16x16x32_bf16(kf0, qf[c], s0, 0, 0, 0);
        s1 = __builtin_amdgcn_mfma_f32_16x16x32_bf16(kf1, qf[c], s1, 0, 0, 0);
      }
      __builtin_amdgcn_s_setprio(0);

      const int qg = wrow0 + lr;
      float x0[4], x1[4];
      if (kc + 31 > wrow0) {
        #pragma unroll
        for (int rr = 0; rr < 4; ++rr) {
          x0[rr] = (kc + 4 * lg + rr      > qg) ? NINF : s0[rr];
          x1[rr] = (kc + 16 + 4 * lg + rr > qg) ? NINF : s1[rr];
        }
      } else {
        #pragma unroll
        for (int rr = 0; rr < 4; ++rr) { x0[rr] = s0[rr]; x1[rr] = s1[rr]; }
      }
      float tm = NINF;
      #pragma unroll
      for (int rr = 0; rr < 4; ++rr) tm = fmaxf(tm, fmaxf(x0[rr], x1[rr]));
      tm = fmaxf(tm, __shfl_xor(tm, 16));
      tm = fmaxf(tm, __shfl_xor(tm, 32));

      if (!__all(tm <= m + 8.0f)) {
        const float mn = fmaxf(m, tm);
        const float al = __builtin_exp2f(m - mn);
        m = mn; l *= al;
        #pragma unroll
        for (int rr = 0; rr < 4; ++rr) {
          const float ar = __shfl(al, 4 * lg + rr);
          #pragma unroll
          for (int ds = 0; ds < 8; ++ds) oacc[ds][rr] *= ar;
        }
      }

      float p0[4], p1[4];
      float ts = 0.f;
      #pragma unroll
      for (int rr = 0; rr < 4; ++rr) {
        p0[rr] = __builtin_exp2f(x0[rr] - m);
        p1[rr] = __builtin_exp2f(x1[rr] - m);
        ts += p0[rr] + p1[rr];
      }
      ts += __shfl_xor(ts, 16);
      ts += __shfl_xor(ts, 32);
      l += ts;

      *reinterpret_cast<unsigned*>(&Ps[wave][lr][4 * lg])          = pk2(p0[0], p0[1]);
      *reinterpret_cast<unsigned*>(&Ps[wave][lr][4 * lg + 2])      = pk2(p0[2], p0[3]);
      *reinterpret_cast<unsigned*>(&Ps[wave][lr][16 + 4 * lg])     = pk2(p1[0], p1[1]);
      *reinterpret_cast<unsigned*>(&Ps[wave][lr][16 + 4 * lg + 2]) = pk2(p1[2], p1[3]);

      const bf16x8 pf = *reinterpret_cast<const bf16x8*>(&Ps[wave][lr][lg * 8]);
      __builtin_amdgcn_s_setprio(1);
      #pragma unroll
      for (int ds = 0; ds < 8; ++ds) {
        const int G = (2 * ds + (lr >> 3)) & 3;
        const bf16x8 vf = *reinterpret_cast<const bf16x8*>(&Vt[ds * 16 + lr][8 * (lg ^ G)]);
        oacc[ds] = __builtin_amdgcn_mfma_f32_16x16x32_bf16(pf, vf, oacc[ds], 0, 0, 0);
      }
      __builtin_amdgcn_s_setprio(0);
    }
  }

  float* aw = ws + (size_t)blk * 8192 + (size_t)(wave * 16) * 128;
  #pragma unroll
  for (int rr = 0; rr < 4; ++rr) {
    #pragma unroll
    for (int ds = 0; ds < 8; ++ds) {
      aw[(4 * lg + rr) * 128 + ds * 16 + lr] = oacc[ds][rr];
    }
  }
  if (lg == 0) {
    float* mlp = ws + ML4_OFF + (size_t)(blk * 64 + wave * 16 + lr) * 2;
    mlp[0] = m;
    mlp[1] = l;
  }
}

__global__ __launch_bounds__(256) void fa_merge4(
    const float* __restrict__ ws, float* __restrict__ O, int S)
{
  const int blk2 = blockIdx.x;          // b*32 + qt
  const int b  = blk2 >> 5;
  const int qt = blk2 & 31;
  const int tid = threadIdx.x;
  const int row = tid >> 2;
  const int c0  = (tid & 3) * 32;

  const int w = (31 - qt) * 16 + b;
  float mi[4], li[4];
  float mm = NINF;
  #pragma unroll
  for (int i = 0; i < 4; ++i) {
    const float* ml = ws + ML4_OFF + (size_t)((i * 512 + w) * 64 + row) * 2;
    mi[i] = ml[0]; li[i] = ml[1];
    mm = fmaxf(mm, mi[i]);
  }
  float a[4], den = 0.f;
  #pragma unroll
  for (int i = 0; i < 4; ++i) { a[i] = __builtin_exp2f(mi[i] - mm); den += a[i] * li[i]; }
  const float inv = 1.0f / den;

  float* out = O + ((size_t)b * S + qt * 64 + row) * DHEAD + c0;
  #pragma unroll
  for (int qd = 0; qd < 8; ++qd) {
    float4 acc = {0.f, 0.f, 0.f, 0.f};
    #pragma unroll
    for (int i = 0; i < 4; ++i) {
      const float* wp = ws + (size_t)(i * 512 + w) * 8192 + (size_t)row * 128 + c0;
      const float4 u = *reinterpret_cast<const float4*>(wp + qd * 4);
      acc.x += a[i] * u.x; acc.y += a[i] * u.y;
      acc.z += a[i] * u.z; acc.w += a[i] * u.w;
    }
    float4 o;
    o.x = acc.x * inv; o.y = acc.y * inv; o.z = acc.z * inv; o.w = acc.w * inv;
    *reinterpret_cast<float4*>(out + qd * 4) = o;
  }
}

// ===================== 2-way split (R11-verified, unchanged) =====================
__global__ __launch_bounds__(256) void fa_split(
    const float* __restrict__ Q, const float* __restrict__ K,
    const float* __restrict__ V, float* __restrict__ ws, int S)
{
  const int bid  = blockIdx.x;
  const int r    = bid >> 8;
  const int i    = bid & 255;
  const int b    = i & 15;
  const int idx  = i >> 4;
  const int qt   = (r < 2) ? (31 - idx) : idx;
  const int half = r & 1;
  const int blk  = bid;

  const int t0 = half * (qt + 1);
  const int t1 = t0 + (qt + 1);

  const int tid  = threadIdx.x;
  const int wave = tid >> 6;
  const int lane = tid & 63;
  const int lr   = lane & 15;
  const int lg   = lane >> 4;

  __shared__ bf16 Ks[2][32][136];
  __shared__ bf16 Vt[2][DHEAD][40];
  __shared__ bf16 Ps[4][16][40];

  const size_t bo = (size_t)b * S * DHEAD;
  const float* Qb = Q + bo + (size_t)qt * 64 * DHEAD;
  const float* Kb = K + bo;
  const float* Vb = V + bo;
  const int wrow0 = qt * 64 + wave * 16;

  const int j   = tid & 31;
  const int prw = tid >> 5;
  const int d4  = j << 2;
  const int Gw  = (j >> 1) & 3;

  bf16x8 qf[4];
  {
    const float* qr = Qb + (size_t)(wave * 16 + lr) * DHEAD;
    #pragma unroll
    for (int c = 0; c < 4; ++c) {
      const float4 u0 = *reinterpret_cast<const float4*>(qr + c * 32 + lg * 8);
      const float4 u1 = *reinterpret_cast<const float4*>(qr + c * 32 + lg * 8 + 4);
      bf16x8 f;
      f[0] = (bf16)u0.x; f[1] = (bf16)u0.y; f[2] = (bf16)u0.z; f[3] = (bf16)u0.w;
      f[4] = (bf16)u1.x; f[5] = (bf16)u1.y; f[6] = (bf16)u1.z; f[7] = (bf16)u1.w;
      qf[c] = f;
    }
  }

  f32x4 oacc[8];
  #pragma unroll
  for (int ii = 0; ii < 8; ++ii) oacc[ii] = (f32x4){0.f, 0.f, 0.f, 0.f};
  float m = NINF, l = 0.f;

  float4 kA[2], kB[2], vA[2], vB[2];
  auto load_tile = [&](int kc) {
    #pragma unroll
    for (int ps = 0; ps < 2; ++ps) {
      const int kv = kc + 2 * (prw + 8 * ps);
      const float* kp = Kb + (size_t)kv * DHEAD + d4;
      const float* vp = Vb + (size_t)kv * DHEAD + d4;
      kA[ps] = *reinterpret_cast<const float4*>(kp);
      kB[ps] = *reinterpret_cast<const float4*>(kp + DHEAD);
      vA[ps] = *reinterpret_cast<const float4*>(vp);
      vB[ps] = *reinterpret_cast<const float4*>(vp + DHEAD);
    }
  };
  auto write_tile = [&](int buf) {
    #pragma unroll
    for (int ps = 0; ps < 2; ++ps) {
      const int kvp = prw + 8 * ps;
      bf16x4 ka, kb;
      ka[0] = (bf16)kA[ps].x; ka[1] = (bf16)kA[ps].y;
      ka[2] = (bf16)kA[ps].z; ka[3] = (bf16)kA[ps].w;
      kb[0] = (bf16)kB[ps].x; kb[1] = (bf16)kB[ps].y;
      kb[2] = (bf16)kB[ps].z; kb[3] = (bf16)kB[ps].w;
      *reinterpret_cast<bf16x4*>(&Ks[buf][2 * kvp][d4])     = ka;
      *reinterpret_cast<bf16x4*>(&Ks[buf][2 * kvp + 1][d4]) = kb;
      const int pS = kvp ^ (Gw << 2);
      const float* fa = &vA[ps].x;
      const float* fb = &vB[ps].x;
      #pragma unroll
      for (int c = 0; c < 4; ++c) {
        *reinterpret_cast<unsigned*>(&Vt[buf][d4 + c][2 * pS]) = pk2(fa[c], fb[c]);
      }
    }
  };

  load_tile(t0 * 32);
  write_tile(0);
  if (t0 + 1 < t1) load_tile((t0 + 1) * 32);

  int cur = 0;
  for (int t = t0; t < t1; ++t) {
    __syncthreads();
    if (t + 1 < t1) write_tile(cur ^ 1);
    if (t + 2 < t1) load_tile((t + 2) * 32);

    const int kc = t * 32;
    if (kc <= wrow0 + 15) {
      f32x4 s0 = {0.f, 0.f, 0.f, 0.f}, s1 = {0.f, 0.f, 0.f, 0.f};
      __builtin_amdgcn_s_setprio(1);
      #pragma unroll
      for (int c = 0; c < 4; ++c) {
        const bf16x8 kf0 = *reinterpret_cast<const bf16x8*>(&Ks[cur][lr][c * 32 + lg * 8]);
        const bf16x8 kf1 = *reinterpret_cast<const bf16x8*>(&Ks[cur][16 + lr][c * 32 + lg * 8]);
        s0 = __builtin_amdgcn_mfma_f32_16x16x32_bf16(kf0, qf[c], s0, 0, 0, 0);
        s1 = __builtin_amdgcn_mfma_f32_16x16x32_bf16(kf1, qf[c], s1, 0, 0, 0);
      }
      __builtin_amdgcn_s_setprio(0);

      const int qg = wrow0 + lr;
      float x0[4], x1[4];
      if (kc + 31 > wrow0) {
        #pragma unroll
        for (int rr = 0; rr < 4; ++rr) {
          x0[rr] = (kc + 4 * lg + rr      > qg) ? NINF : s0[rr] * SCL2;
          x1[rr] = (kc + 16 + 4 * lg + rr > qg) ? NINF : s1[rr] * SCL2;
        }
      } else {
        #pragma unroll
        for (int rr = 0; rr < 4; ++rr) { x0[rr] = s0[rr] * SCL2; x1[rr] = s1[rr] * SCL2; }
      }
      float tm = NINF;
      #pragma unroll
      for (int rr = 0; rr < 4; ++rr) tm = fmaxf(tm, fmaxf(x0[rr], x1[rr]));
      tm = fmaxf(tm, __shfl_xor(tm, 16));
      tm = fmaxf(tm, __shfl_xor(tm, 32));

      if (!__all(tm <= m + 8.0f)) {
        const float mn = fmaxf(m, tm);
        const float al = __builtin_exp2f(m - mn);
        m = mn; l *= al;
        #pragma unroll
        for (int rr = 0; rr < 4; ++rr) {
          const float ar = __shfl(al, 4 * lg + rr);
          #pragma unroll
          for (int ds = 0; ds < 8; ++ds) oacc[ds][rr] *= ar;
        }
      }

      float p0[4], p1[4];
      float ts = 0.f;
      #pragma unroll
      for (int rr = 0; rr < 4; ++rr) {
        p0[rr] = __builtin_exp2f(x0[rr] - m);
        p1[rr] = __builtin_exp2f(x1[rr] - m);
        ts += p0[rr] + p1[rr];
      }
      ts += __shfl_xor(ts, 16);
      ts += __shfl_xor(ts, 32);
      l += ts;

      *reinterpret_cast<unsigned*>(&Ps[wave][lr][4 * lg])          = pk2(p0[0], p0[1]);
      *reinterpret_cast<unsigned*>(&Ps[wave][lr][4 * lg + 2])      = pk2(p0[2], p0[3]);
      *reinterpret_cast<unsigned*>(&Ps[wave][lr][16 + 4 * lg])     = pk2(p1[0], p1[1]);
      *reinterpret_cast<unsigned*>(&Ps[wave][lr][16 + 4 * lg + 2]) = pk2(p1[2], p1[3]);

      const bf16x8 pf = *reinterpret_cast<const bf16x8*>(&Ps[wave][lr][lg * 8]);
      __builtin_amdgcn_s_setprio(1);
      #pragma unroll
      for (int ds = 0; ds < 8; ++ds) {
        const int G = (2 * ds + (lr >> 3)) & 3;
        const bf16x8 vf = *reinterpret_cast<const bf16x8*>(&Vt[cur][ds * 16 + lr][8 * (lg ^ G)]);
        oacc[ds] = __builtin_amdgcn_mfma_f32_16x16x32_bf16(pf, vf, oacc[ds], 0, 0, 0);
      }
      __builtin_amdgcn_s_setprio(0);
    }
    cur ^= 1;
  }

  float* aw = ws + (size_t)blk * 8192 + (size_t)(wave * 16) * 128;
  #pragma unroll
  for (int rr = 0; rr < 4; ++rr) {
    #pragma unroll
    for (int ds = 0; ds < 8; ++ds) {
      aw[(4 * lg + rr) * 128 + ds * 16 + lr] = oacc[ds][rr];
    }
  }
  if (lg == 0) {
    float* mlp = ws + ML_OFF + (size_t)(blk * 64 + wave * 16 + lr) * 2;
    mlp[0] = m;
    mlp[1] = l;
  }
}

__global__ __launch_bounds__(256) void fa_merge(
    const float* __restrict__ ws, float* __restrict__ O, int S)
{
  const int blk2 = blockIdx.x;
  const int b  = blk2 >> 5;
  const int qt = blk2 & 31;
  const int tid = threadIdx.x;
  const int row = tid >> 2;
  const int c0  = (tid & 3) * 32;

  const int idx  = (qt >= 16) ? (31 - qt) : qt;
  const int base = (qt >= 16) ? 0 : 512;
  const int blk0 = base + (idx << 4) + b;
  const int blk1 = blk0 + 256;

  const float* ml0 = ws + ML_OFF + (size_t)(blk0 * 64 + row) * 2;
  const float* ml1 = ws + ML_OFF + (size_t)(blk1 * 64 + row) * 2;
  const float m0 = ml0[0], l0 = ml0[1];
  const float m1 = ml1[0], l1 = ml1[1];
  const float mm = fmaxf(m0, m1);
  const float a0 = __builtin_exp2f(m0 - mm);
  const float a1 = __builtin_exp2f(m1 - mm);
  const float inv = 1.0f / (a0 * l0 + a1 * l1);

  const float* w0 = ws + (size_t)blk0 * 8192 + (size_t)row * 128 + c0;
  const float* w1 = ws + (size_t)blk1 * 8192 + (size_t)row * 128 + c0;
  float* out = O + ((size_t)b * S + qt * 64 + row) * DHEAD + c0;

  #pragma unroll
  for (int qd = 0; qd < 8; ++qd) {
    const float4 u0 = *reinterpret_cast<const float4*>(w0 + qd * 4);
    const float4 u1 = *reinterpret_cast<const float4*>(w1 + qd * 4);
    float4 o;
    o.x = (a0 * u0.x + a1 * u1.x) * inv;
    o.y = (a0 * u0.y + a1 * u1.y) * inv;
    o.z = (a0 * u0.z + a1 * u1.z) * inv;
    o.w = (a0 * u0.w + a1 * u1.w) * inv;
    *reinterpret_cast<float4*>(out + qd * 4) = o;
  }
}

// ===================== fallback (R5-verified, unchanged) =====================
__global__ __launch_bounds__(256) void fa_fwd(
    const float* __restrict__ Q, const float* __restrict__ K,
    const float* __restrict__ V, float* __restrict__ O, int S)
{
  const int bid = blockIdx.x;
  const int prb = bid & 255;
  const int hb  = bid >> 8;
  const int b   = prb & 15;
  const int jj  = prb >> 4;
  const int qt  = hb ? jj : (31 - jj);

  const int tid  = threadIdx.x;
  const int wave = tid >> 6;
  const int lane = tid & 63;
  const int lr   = lane & 15;
  const int lg   = lane >> 4;

  __shared__ bf16 Ks[2][32][136];
  __shared__ bf16 Vt[2][DHEAD][40];
  __shared__ bf16 Ps[4][16][40];

  const size_t bo = (size_t)b * S * DHEAD;
  const float* Qb = Q + bo + (size_t)qt * 64 * DHEAD;
  const float* Kb = K + bo;
  const float* Vb = V + bo;
  const int wrow0 = qt * 64 + wave * 16;

  const int j   = tid & 31;
  const int prw = tid >> 5;
  const int d4  = j << 2;
  const int Gw  = (j >> 1) & 3;

  bf16x8 qf[4];
  {
    const float* qr = Qb + (size_t)(wave * 16 + lr) * DHEAD;
    #pragma unroll
    for (int c = 0; c < 4; ++c) {
      const float4 u0 = *reinterpret_cast<const float4*>(qr + c * 32 + lg * 8);
      const float4 u1 = *reinterpret_cast<const float4*>(qr + c * 32 + lg * 8 + 4);
      bf16x8 f;
      f[0] = (bf16)u0.x; f[1] = (bf16)u0.y; f[2] = (bf16)u0.z; f[3] = (bf16)u0.w;
      f[4] = (bf16)u1.x; f[5] = (bf16)u1.y; f[6] = (bf16)u1.z; f[7] = (bf16)u1.w;
      qf[c] = f;
    }
  }

  f32x4 oacc[8];
  #pragma unroll
  for (int ii = 0; ii < 8; ++ii) oacc[ii] = (f32x4){0.f, 0.f, 0.f, 0.f};
  float m = NINF, l = 0.f;

  const int nt = 2 * (qt + 1);
  float4 kA[2], kB[2], vA[2], vB[2];

  auto load_tile = [&](int kc) {
    #pragma unroll
    for (int ps = 0; ps < 2; ++ps) {
      const int kv = kc + 2 * (prw + 8 * ps);
      const float* kp = Kb + (size_t)kv * DHEAD + d4;
      const float* vp = Vb + (size_t)kv * DHEAD + d4;
      kA[ps] = *reinterpret_cast<const float4*>(kp);
      kB[ps] = *reinterpret_cast<const float4*>(kp + DHEAD);
      vA[ps] = *reinterpret_cast<const float4*>(vp);
      vB[ps] = *reinterpret_cast<const float4*>(vp + DHEAD);
    }
  };
  auto write_tile = [&](int buf) {
    #pragma unroll
    for (int ps = 0; ps < 2; ++ps) {
      const int kvp = prw + 8 * ps;
      bf16x4 ka, kb;
      ka[0] = (bf16)kA[ps].x; ka[1] = (bf16)kA[ps].y;
      ka[2] = (bf16)kA[ps].z; ka[3] = (bf16)kA[ps].w;
      kb[0] = (bf16)kB[ps].x; kb[1] = (bf16)kB[ps].y;
      kb[2] = (bf16)kB[ps].z; kb[3] = (bf16)kB[ps].w;
      *reinterpret_cast<bf16x4*>(&Ks[buf][2 * kvp][d4])     = ka;
      *reinterpret_cast<bf16x4*>(&Ks[buf][2 * kvp + 1][d4]) = kb;
      const int pS = kvp ^ (Gw << 2);
      const float* fa = &vA[ps].x;
      const float* fb = &vB[ps].x;
      #pragma unroll
      for (int c = 0; c < 4; ++c) {
        *reinterpret_cast<unsigned*>(&Vt[buf][d4 + c][2 * pS]) = pk2(fa[c], fb[c]);
      }
    }
  };

  load_tile(0);
  write_tile(0);
  if (nt > 1) load_tile(32);

  int cur = 0;
  for (int t = 0; t < nt; ++t) {
    __syncthreads();
    if (t + 1 < nt) write_tile(cur ^ 1);
    if (t + 2 < nt) load_tile((t + 2) * 32);

    const int kc = t * 32;
    if (kc <= wrow0 + 15) {
      f32x4 s0 = {0.f, 0.f, 0.f, 0.f}, s1 = {0.f, 0.f, 0.f, 0.f};
      __builtin_amdgcn_s_setprio(1);
      #pragma unroll
      for (int c = 0; c < 4; ++c) {
        const bf16x8 kf0 = *reinterpret_cast<const bf16x8*>(&Ks[cur][lr][c * 32 + lg * 8]);
        const bf16x8 kf1 = *reinterpret_cast<const bf16x8*>(&Ks[cur][16 + lr][c * 32 + lg * 8]);
        s0 = __builtin_amdgcn_mfma_f32_16x16x32_bf16(kf0, qf[c], s0, 0, 0, 0);
        s1 = __builtin_amdgcn_mfma_f32_16x16x32_bf16(kf1, qf[c], s1, 0, 0, 0);
      }
      __builtin_amdgcn_s_setprio(0);

      const int qg = wrow0 + lr;
      float x0[4], x1[4];
      if (kc + 31 > wrow0) {
        #pragma unroll
        for (int rr = 0; rr < 4; ++rr) {
          x0[rr] = (kc + 4 * lg + rr      > qg) ? NINF : s0[rr] * SCL2;
          x1[rr] = (kc + 16 + 4 * lg + rr > qg) ? NINF : s1[rr] * SCL2;
        }
      } else {
        #pragma unroll
        for (int rr = 0; rr < 4; ++rr) { x0[rr] = s0[rr] * SCL2; x1[rr] = s1[rr] * SCL2; }
      }
      float tm = NINF;
      #pragma unroll
      for (int rr = 0; rr < 4; ++rr) tm = fmaxf(tm, fmaxf(x0[rr], x1[rr]));
      tm = fmaxf(tm, __shfl_xor(tm, 16));
      tm = fmaxf(tm, __shfl_xor(tm, 32));

      if (!__all(tm <= m + 8.0f)) {
        const float mn = fmaxf(m, tm);
        const float al = __builtin_exp2f(m - mn);
        m = mn; l *= al;
        #pragma unroll
        for (int rr = 0; rr < 4; ++rr) {
          const float ar = __shfl(al, 4 * lg + rr);
          #pragma unroll
          for (int ds = 0; ds < 8; ++ds) oacc[ds][rr] *= ar;
        }
      }

      float p0[4], p1[4];
      float ts = 0.f;
      #pragma unroll
      for (int rr = 0; rr < 4; ++rr) {
        p0[rr] = __builtin_exp2f(x0[rr] - m);
        p1[rr] = __builtin_exp2f(x1[rr] - m);
        ts += p0[rr] + p1[rr];
      }
      ts += __shfl_xor(ts, 16);
      ts += __shfl_xor(ts, 32);
      l += ts;

      *reinterpret_cast<unsigned*>(&Ps[wave][lr][4 * lg])          = pk2(p0[0], p0[1]);
      *reinterpret_cast<unsigned*>(&Ps[wave][lr][4 * lg + 2])      = pk2(p0[2], p0[3]);
      *reinterpret_cast<unsigned*>(&Ps[wave][lr][16 + 4 * lg])     = pk2(p1[0], p1[1]);
      *reinterpret_cast<unsigned*>(&Ps[wave][lr][16 + 4 * lg + 2]) = pk2(p1[2], p1[3]);

      const bf16x8 pf = *reinterpret_cast<const bf16x8*>(&Ps[wave][lr][lg * 8]);
      __builtin_amdgcn_s_setprio(1);
      #pragma unroll
      for (int ds = 0; ds < 8; ++ds) {
        const int G = (2 * ds + (lr >> 3)) & 3;
        const bf16x8 vf = *reinterpret_cast<const bf16x8*>(&Vt[cur][ds * 16 + lr][8 * (lg ^ G)]);
        oacc[ds] = __builtin_amdgcn_mfma_f32_16x16x32_bf16(pf, vf, oacc[ds], 0, 0, 0);
      }
      __builtin_amdgcn_s_setprio(0);
    }
    cur ^= 1;
  }

  const float linv = 1.0f / l;
  float* Ob = O + bo + (size_t)(qt * 64 + wave * 16) * DHEAD;
  #pragma unroll
  for (int rr = 0; rr < 4; ++rr) {
    const float ir = __shfl(linv, 4 * lg + rr);
    #pragma unroll
    for (int ds = 0; ds < 8; ++ds) {
      Ob[(size_t)(4 * lg + rr) * DHEAD + ds * 16 + lr] = oacc[ds][rr] * ir;
    }
  }
}

extern "C" void kernel_launch(void* const* d_in, const int* in_sizes, int n_in,
                              void* d_out, int out_size, void* d_ws, size_t ws_size,
                              hipStream_t stream) {
  const float* q = (const float*)d_in[0];
  const float* k = (const float*)d_in[1];
  const float* v = (const float*)d_in[2];
  float* o = (float*)d_out;

  const int B = 16;
  const int S = in_sizes[0] / (B * DHEAD);   // 2048

  if (ws_size >= WS_NEED4 && S == 2048) {
    float* ws = (float*)d_ws;
    fa_split4<<<dim3(2048), dim3(256), 0, stream>>>(q, k, v, ws, S);
    fa_merge4<<<dim3(512), dim3(256), 0, stream>>>(ws, o, S);
  } else if (ws_size >= WS_NEED && S == 2048) {
    float* ws = (float*)d_ws;
    fa_split<<<dim3(1024), dim3(256), 0, stream>>>(q, k, v, ws, S);
    fa_merge<<<dim3(512), dim3(256), 0, stream>>>(ws, o, S);
  } else {
    fa_fwd<<<dim3(512), dim3(256), 0, stream>>>(q, k, v, o, S);
  }
}